// Round 11
// baseline (7560.754 us; speedup 1.0000x reference)
//
#include <hip/hip_runtime.h>
#include <stdint.h>

// Online Neural CDE, fused persistent kernel — fp32 datapath, 512-thread
// blocks, TAGGED-PAYLOAD DATAFLOW exchange (no barriers, no flags).
// 8 groups x 32 blocks; group = 16 batches; each block holds a 1/32
// output-row-slice of the vector-field weights in LDS.
// Every cross-block word is an 8-byte atomic (float value, uint32 epoch tag);
// consumers poll their own words until the tag matches. This removes the
// vmcnt-drain + flag-store + flag-poll chain (~3 serial L3 RTs/phase) that
// R10 showed dominates (VALUBusy 13.6%, time invariant to compute cuts).
// WAR safety is inherent: writing epoch n+1 of any buffer transitively
// requires all blocks to have read epoch n (full-buffer reads per phase).

#define NGRP 8
#define NJ   32
#define NTHR 512
#define STW  276   // dword stride for 256-col tiles (4-dword gap per 64 cols)
#define STY  132   // dword stride for 128-col y tile (gap at col 64)
#define GSTRIDE 18432  // u64 words per group: yw 4096 | kw 2048 | h1/h2/h3 4096*3

typedef unsigned long long u64t;

static __device__ __forceinline__ u64t ld_coh8(const u64t* p) {
  return __hip_atomic_load(p, __ATOMIC_RELAXED, __HIP_MEMORY_SCOPE_AGENT);
}
static __device__ __forceinline__ void st_coh8(u64t* p, u64t v) {
  __hip_atomic_store(p, v, __ATOMIC_RELAXED, __HIP_MEMORY_SCOPE_AGENT);
}
static __device__ __forceinline__ u64t pack_tf(float f, uint32_t tag) {
  union { float f; uint32_t u; } c; c.f = f;
  return ((u64t)tag << 32) | c.u;
}
static __device__ __forceinline__ float low_f(u64t v) {
  union { uint32_t u; float f; } c; c.u = (uint32_t)v;
  return c.f;
}

// softplus(x) = max(x,0) + log(1+exp(-|x|)) — fast intrinsics
static __device__ __forceinline__ float sp(float x) {
  return fmaxf(x, 0.f) + __logf(1.f + __expf(-fabsf(x)));
}
// tanh via __expf + v_rcp; saturates correctly for large |x|
static __device__ __forceinline__ float tanh_fast(float x) {
  float ax = fabsf(x);
  float e = __expf(ax + ax);
  float t = 1.f - 2.f * __builtin_amdgcn_rcpf(e + 1.f);
  return __builtin_copysignf(t, x);
}

// np.searchsorted(kn, t, 'right') - 1, clipped to [0, 62]; 64 knots.
static __device__ __forceinline__ int seg_idx(const float* kn, float t) {
  int lo = 0, hi = 64;
  while (lo < hi) { int mid = (lo + hi) >> 1; if (kn[mid] <= t) lo = mid + 1; else hi = mid; }
  int jj = lo - 1;
  return jj < 0 ? 0 : (jj > 62 ? 62 : jj);
}

static __device__ __forceinline__ float dot4(float4 w, float4 a, float acc) {
  acc = fmaf(w.x, a.x, acc);
  acc = fmaf(w.y, a.y, acc);
  acc = fmaf(w.z, a.z, acc);
  return fmaf(w.w, a.w, acc);
}

__global__ void __launch_bounds__(NTHR)
ncde_kernel(const float* __restrict__ ts, const float* __restrict__ tsi,
            const float* __restrict__ obs, const float* __restrict__ tmax,
            const float* __restrict__ i_win, const float* __restrict__ i_bin,
            const float* __restrict__ i_wmid, const float* __restrict__ i_bmid,
            const float* __restrict__ i_wout, const float* __restrict__ i_bout,
            const float* __restrict__ v_win, const float* __restrict__ v_bin,
            const float* __restrict__ v_wmid, const float* __restrict__ v_bmid,
            const float* __restrict__ v_wout, const float* __restrict__ v_bout,
            float* __restrict__ out, u64t* __restrict__ ws)
{
  __shared__ __align__(16) float w_l4[64][STW];   // v_wout rows 64j..64j+63
  __shared__ __align__(16) float w_m0[8][STW];    // v_wmid[0] rows 8j..
  __shared__ __align__(16) float w_m1[8][STW];    // v_wmid[1] rows 8j..
  __shared__ __align__(16) float w_l1[8][STY];    // v_win rows 8j..
  __shared__ __align__(16) float s_act[16][STW];  // staged activations (16 b)
  __shared__ __align__(16) float s_y[16][STY];    // staged y input
  __shared__ __align__(16) float s_ts[16][64];
  __shared__ __align__(16) float s_kn[16][64];
  __shared__ float s_dx[16][16];
  __shared__ float s_part[2][8][9];               // L4 partials [set][bb][w8]
  __shared__ unsigned char s_sj[16][128];         // searchsorted table (bb,ti)
  __shared__ float s_dt[16], s_tm[16];
  __shared__ float sb_l1[8], sb_m0[8], sb_m1[8], sb_l4[64];

  const int tid = threadIdx.x;
  const int bid = blockIdx.x;
  const int g = bid & 7;    // group (== XCD under round-robin; perf only)
  const int j = bid >> 3;   // slice 0..31

  u64t* gbase = ws + (size_t)g * GSTRIDE;
  u64t* yw = gbase;          // [2][16][128] tagged
  u64t* kw = gbase + 4096;   // [16][128] tagged
  u64t* h1 = gbase + 6144;   // [16][256] tagged
  u64t* h2 = gbase + 10240;
  u64t* h3 = gbase + 14336;

  // ---------------- load weight slices -> LDS (fp32, gapped cols) ----------
  for (int e2 = tid; e2 < 64 * 64; e2 += NTHR) {   // w_l4: 64 rows x 64 f4
    int r = e2 >> 6, c4 = e2 & 63; int k = 4 * c4;
    float4 v = *(const float4*)(v_wout + (size_t)(64 * j + r) * 256 + k);
    *(float4*)&w_l4[r][k + 4 * (k >> 6)] = v;
  }
  for (int e2 = tid; e2 < 8 * 64; e2 += NTHR) {    // mids: 8 rows x 64 f4 each
    int r = e2 >> 6, c4 = e2 & 63; int k = 4 * c4;
    float4 a = *(const float4*)(v_wmid + (size_t)(8 * j + r) * 256 + k);
    float4 b2 = *(const float4*)(v_wmid + 65536 + (size_t)(8 * j + r) * 256 + k);
    int col = k + 4 * (k >> 6);
    *(float4*)&w_m0[r][col] = a;
    *(float4*)&w_m1[r][col] = b2;
  }
  if (tid < 256) {                                 // w_l1: 8 rows x 32 f4
    int r = tid >> 5, c4 = tid & 31; int k = 4 * c4;
    float4 v = *(const float4*)(v_win + (size_t)(8 * j + r) * 128 + k);
    *(float4*)&w_l1[r][k + 4 * (k >> 6)] = v;
  }
  if (tid < 8) {
    sb_l1[tid] = v_bin[8 * j + tid];
    sb_m0[tid] = v_bmid[8 * j + tid];
    sb_m1[tid] = v_bmid[256 + 8 * j + tid];
  }
  if (tid < 64) sb_l4[tid] = v_bout[64 * j + tid];
  for (int e2 = tid; e2 < 16 * 64; e2 += NTHR) {
    int bb = e2 >> 6, i2 = e2 & 63;
    int b = g * 16 + bb;
    s_ts[bb][i2] = ts[b * 64 + i2];
    s_kn[bb][i2] = tsi[b * 64 + i2];
  }
  if (tid < 16) s_tm[tid] = tmax[g * 16 + tid];
  __syncthreads();

  // -------- precompute searchsorted table: ti = 2l (t_l), 2l+1 (mid) -------
  for (int e2 = tid; e2 < 2048; e2 += NTHR) {
    int bb = e2 >> 7, ti = e2 & 127;
    if (ti < 127) {
      int li = ti >> 1;
      float te = (ti & 1) ? fmaf(0.5f, s_ts[bb][li + 1] - s_ts[bb][li], s_ts[bb][li])
                          : s_ts[bb][li];
      s_sj[bb][ti] = (unsigned char)seg_idx(&s_kn[bb][0], te);
    }
  }
  __syncthreads();

  // per-word tag poll (spin a little, then sleep; bounded failsafe)
  auto pollv = [&](const u64t* p, u64t v, uint32_t tag) -> u64t {
    uint32_t n = 0;
    while ((uint32_t)(v >> 32) != tag) {
      if (n > 4) __builtin_amdgcn_s_sleep(2);
      if (++n > (1u << 14)) break;   // bounded: no hang (bad data, not timeout)
      v = ld_coh8(p);
    }
    return v;
  };

  // poll-stage a tagged [16][256] h buffer into gapped s_act (8 words/thread)
  auto stageH = [&](const u64t* hp, uint32_t tag) {
    u64t v[8];
    const u64t* p = hp + tid;
#pragma unroll
    for (int it = 0; it < 8; ++it) v[it] = ld_coh8(p + it * NTHR);
#pragma unroll
    for (int it = 0; it < 8; ++it) {
      v[it] = pollv(p + it * NTHR, v[it], tag);
      int e2 = tid + it * NTHR;
      int bb = e2 >> 8, c = e2 & 255;
      s_act[bb][c + 4 * (c >> 6)] = low_f(v[it]);
    }
  };

  // poll-stage y (+ c*dt*k) into s_y (4 words/thread each of yw/kw)
  auto stageY = [&](int cur, int l, int e, uint32_t idx) {
    const u64t* yp = yw + (size_t)cur * 2048;
    const uint32_t ty = (uint32_t)(l >> 1) + 1;
    u64t vy[4], vk[4];
#pragma unroll
    for (int it = 0; it < 4; ++it) vy[it] = ld_coh8(yp + tid + it * NTHR);
    if (e > 0) {
#pragma unroll
      for (int it = 0; it < 4; ++it) vk[it] = ld_coh8(kw + tid + it * NTHR);
    }
#pragma unroll
    for (int it = 0; it < 4; ++it) {
      vy[it] = pollv(yp + tid + it * NTHR, vy[it], ty);
      float yv = low_f(vy[it]);
      int e2 = tid + it * NTHR;
      int bb = e2 >> 7, c2 = e2 & 127;
      if (e > 0) {
        vk[it] = pollv(kw + tid + it * NTHR, vk[it], idx);
        float cd = ((e == 3) ? 1.f : 0.5f) * s_dt[bb];
        yv = fmaf(cd, low_f(vk[it]), yv);
      }
      s_y[bb][c2 + 4 * (c2 >> 6)] = yv;
    }
  };

  // L1: 128-in (s_y) -> 8-row slice, softplus. bb16(0-3) kq4(4-5) o8(6-8)
  auto L1f = [&](uint32_t tag) {
    int bb = tid & 15, kq = (tid >> 4) & 3, o = tid >> 6;
    int off = kq * 32 + 4 * (kq >> 1);
    float acc = 0.f;
    const float* wr = &w_l1[o][off];
    const float* ar = &s_y[bb][off];
#pragma unroll
    for (int c = 0; c < 8; ++c)
      acc = dot4(*(const float4*)(wr + 4 * c), *(const float4*)(ar + 4 * c), acc);
    acc += __shfl_xor(acc, 16);
    acc += __shfl_xor(acc, 32);
    if (kq == 0)
      st_coh8(&h1[bb * 256 + 8 * j + o], pack_tf(sp(acc + sb_l1[o]), tag));
  };

  // mid: 256-in (s_act) -> 8-row slice, softplus. bb16 kq4 o8
  auto midf = [&](const float (*W)[STW], const float* bias, u64t* hdst,
                  uint32_t tag) {
    int bb = tid & 15, kq = (tid >> 4) & 3, o = tid >> 6;
    float acc = 0.f;
    const float* wr = &W[o][68 * kq];
    const float* ar = &s_act[bb][68 * kq];
#pragma unroll
    for (int c = 0; c < 16; ++c)
      acc = dot4(*(const float4*)(wr + 4 * c), *(const float4*)(ar + 4 * c), acc);
    acc += __shfl_xor(acc, 16);
    acc += __shfl_xor(acc, 32);
    if (kq == 0)
      st_coh8(&hdst[bb * 256 + 8 * j + o], pack_tf(sp(acc + bias[o]), tag));
  };

  // L4: one thread = weight row r x both sets (bb, bb+8). bb8 rlo8 w8.
  auto L4f = [&](int e, int cur, int nxt, int l, uint32_t idx, float& ka) {
    const int bb = tid & 7, rlo = (tid >> 3) & 7, w8 = tid >> 6;
    const int r = (w8 << 3) | rlo;                 // slice row 0..63
    const float* wr = &w_l4[r][0];
    const float* arA = &s_act[bb][0];
    const float* arB = &s_act[8 + bb][0];
    float a0 = 0.f, a1 = 0.f, b0 = 0.f, b1 = 0.f;
#pragma unroll
    for (int c4 = 0; c4 < 64; c4 += 2) {
      int o0 = 4 * c4 + 4 * (c4 >> 4);
      int o1 = 4 * (c4 + 1) + 4 * ((c4 + 1) >> 4);
      float4 w0 = *(const float4*)(wr + o0);
      float4 w1 = *(const float4*)(wr + o1);
      a0 = dot4(w0, *(const float4*)(arA + o0), a0);
      a1 = dot4(w1, *(const float4*)(arA + o1), a1);
      b0 = dot4(w0, *(const float4*)(arB + o0), b0);
      b1 = dot4(w1, *(const float4*)(arB + o1), b1);
    }
    float bz = sb_l4[r];
    float zA = a0 + a1 + bz, zB = b0 + b1 + bz;
    float vA = tanh_fast(zA) * s_dx[bb][r & 15];
    float vB = tanh_fast(zB) * s_dx[8 + bb][r & 15];
    vA += __shfl_xor(vA, 8); vA += __shfl_xor(vA, 16); vA += __shfl_xor(vA, 32);
    vB += __shfl_xor(vB, 8); vB += __shfl_xor(vB, 16); vB += __shfl_xor(vB, 32);
    if (rlo == 0) {
      s_part[0][bb][w8] = vA;
      s_part[1][bb][w8] = vB;
    }
    __syncthreads();
    if (tid < 64) {
      int set = tid >> 5, bbw = tid & 7, hl = (tid >> 3) & 3;
      float kv = s_part[set][bbw][2 * hl] + s_part[set][bbw][2 * hl + 1];
      int bbg = 8 * set + bbw;
      int hg = 4 * j + hl;
      if (e == 0) ka = kv;
      else ka = fmaf((e == 3) ? 1.f : 2.f, kv, ka);
      if (e == 3) {
        // read y (tag already satisfied this eval via stageY), compute yn
        // BEFORE the kw store so the y-load data-flows ahead of it (WAR).
        float yo = low_f(ld_coh8(&yw[(size_t)cur * 2048 + bbg * 128 + hg]));
        float dt = s_dt[bbg];
        float yn = yo + dt * (1.f / 6.f) * ka;
        uint32_t wtag = (uint32_t)((l + 1) >> 1) + 1;
        st_coh8(&yw[(size_t)nxt * 2048 + bbg * 128 + hg], pack_tf(yn, wtag));
        int b = g * 16 + bbg;
        out[(size_t)b * 8192 + (size_t)(l + 1) * 128 + hg] =
            (s_ts[bbg][l + 1] <= s_tm[bbg]) ? yn : -99.f;
        st_coh8(&kw[bbg * 128 + hg], pack_tf(kv, idx + 1));
      } else {
        st_coh8(&kw[bbg * 128 + hg], pack_tf(kv, idx + 1));
      }
    }
  };

  // ---------------- init MLP: y0 = MLP_i(x0), weights from global ----------
  if (tid < 256) {
    int bb = tid >> 4, d = tid & 15;
    float t0 = s_ts[bb][0];
    int sj = seg_idx(&s_kn[bb][0], t0);
    float k0 = s_kn[bb][sj], k1 = s_kn[bb][sj + 1];
    float fr = (t0 - k0) / (k1 - k0);
    const float* ob = obs + ((size_t)(g * 16 + bb) * 64 + sj) * 16 + d;
    float o0 = ob[0], o1 = ob[16];
    s_y[bb][d] = fmaf(fr, o1 - o0, o0);
  }
  __syncthreads();
  if (tid < 128) {  // L1i: 16-in, 8-row slice -> h1 tag 1
    int bb = tid & 15, o = tid >> 4;
    float acc = i_bin[8 * j + o];
    const float* wr = i_win + (size_t)(8 * j + o) * 16;
#pragma unroll
    for (int i2 = 0; i2 < 16; ++i2) acc = fmaf(wr[i2], s_y[bb][i2], acc);
    st_coh8(&h1[bb * 256 + 8 * j + o], pack_tf(sp(acc), 1u));
  }
  for (int layer = 0; layer < 2; ++layer) {  // mid-i: bb16 kq4 o8
    stageH(layer == 0 ? h1 : h2, 1u);
    __syncthreads();
    int bb = tid & 15, kq = (tid >> 4) & 3, o = tid >> 6;
    float acc = 0.f;
    const float* wr = i_wmid + (size_t)layer * 65536 + (size_t)(8 * j + o) * 256 + kq * 64;
    const float* ar = &s_act[bb][68 * kq];
#pragma unroll
    for (int c = 0; c < 16; ++c)
      acc = dot4(*(const float4*)(wr + 4 * c), *(const float4*)(ar + 4 * c), acc);
    acc += __shfl_xor(acc, 16);
    acc += __shfl_xor(acc, 32);
    if (kq == 0) {
      u64t* hdst = (layer == 0 ? h2 : h3);
      st_coh8(&hdst[bb * 256 + 8 * j + o],
              pack_tf(sp(acc + i_bmid[layer * 256 + 8 * j + o]), 1u));
    }
    __syncthreads();
  }
  {  // L4i: 4-row slice of 128-wide y0, identity -> yw[0] tag 1 + out row 0
    stageH(h3, 1u);
    __syncthreads();
    if (tid < 256) {
      int bb = tid & 15, kq4 = (tid >> 4) & 3, rl = tid >> 6;
      float acc = 0.f;
      const float* wr = i_wout + (size_t)(4 * j + rl) * 256 + kq4 * 64;
      const float* ar = &s_act[bb][kq4 * 68];
#pragma unroll
      for (int c = 0; c < 16; ++c)
        acc = dot4(*(const float4*)(wr + 4 * c), *(const float4*)(ar + 4 * c), acc);
      acc += __shfl_xor(acc, 16);
      acc += __shfl_xor(acc, 32);
      if (kq4 == 0) {
        int hg = 4 * j + rl;
        float y0 = acc + i_bout[hg];
        st_coh8(&yw[bb * 128 + hg], pack_tf(y0, 1u));
        int b = g * 16 + bb;
        out[(size_t)b * 8192 + hg] = (s_ts[bb][0] <= s_tm[bb]) ? y0 : -99.f;
      }
    }
    __syncthreads();
  }

  // -------- RK4 over 63 intervals: 4 dataflow phases per eval --------------
  float ka = 0.f;   // RK4 accumulator (owner lanes tid<64)

#pragma unroll 1
  for (int l = 0; l < 63; ++l) {
    const int cur = l & 1, nxt = cur ^ 1;
#pragma unroll 1
    for (int e = 0; e < 4; ++e) {
      const uint32_t idx = (uint32_t)(l * 4 + e);   // 0..251
      const uint32_t th = idx + 2u;                  // h-buffer tag this eval
      // ---- phase 1: stage y/k (tag-poll), prologue, L1 -> h1 ----
      if (e == 0 && tid < 16) s_dt[tid] = s_ts[tid][l + 1] - s_ts[tid][l];
      if (tid < 256) {  // dx(t_e) via precomputed seg table
        int bb = tid >> 4, d = tid & 15;
        int ti = 2 * l + ((e == 0) ? 0 : ((e == 3) ? 2 : 1));
        int sj = s_sj[bb][ti];
        const float* ob = obs + ((size_t)(g * 16 + bb) * 64 + sj) * 16 + d;
        s_dx[bb][d] = (ob[16] - ob[0]) / (s_kn[bb][sj + 1] - s_kn[bb][sj]);
      }
      stageY(cur, l, e, idx);
      __syncthreads();
      L1f(th);
      __syncthreads();
      // ---- phase 2: h1 -> mid0 -> h2 ----
      stageH(h1, th);
      __syncthreads();
      midf(w_m0, sb_m0, h2, th);
      __syncthreads();
      // ---- phase 3: h2 -> mid1 -> h3 ----
      stageH(h2, th);
      __syncthreads();
      midf(w_m1, sb_m1, h3, th);
      __syncthreads();
      // ---- phase 4: h3 -> L4 -> kw (tag idx+1), y-commit at e3 ----
      stageH(h3, th);
      __syncthreads();
      L4f(e, cur, nxt, l, idx, ka);
      // (no trailing sync needed: next phase-1 touches s_y/s_dx only, and
      //  all s_act/s_part readers completed before L4f's internal barrier)
    }
  }
}

extern "C" void kernel_launch(void* const* d_in, const int* in_sizes, int n_in,
                              void* d_out, int out_size, void* d_ws, size_t ws_size,
                              hipStream_t stream) {
  const float* ts     = (const float*)d_in[0];
  const float* tsi    = (const float*)d_in[1];
  const float* obs    = (const float*)d_in[2];
  const float* tmaxp  = (const float*)d_in[3];
  const float* i_win  = (const float*)d_in[4];
  const float* i_bin  = (const float*)d_in[5];
  const float* i_wmid = (const float*)d_in[6];
  const float* i_bmid = (const float*)d_in[7];
  const float* i_wout = (const float*)d_in[8];
  const float* i_bout = (const float*)d_in[9];
  const float* v_win  = (const float*)d_in[10];
  const float* v_bin  = (const float*)d_in[11];
  const float* v_wmid = (const float*)d_in[12];
  const float* v_bmid = (const float*)d_in[13];
  const float* v_wout = (const float*)d_in[14];
  const float* v_bout = (const float*)d_in[15];

  // zero ALL tagged payload (tags restart each launch; replay-safe)
  size_t payload = (size_t)NGRP * GSTRIDE * 8;   // 1,179,648 B
  if (payload > ws_size) payload = ws_size;
  (void)hipMemsetAsync(d_ws, 0, payload, stream);

  ncde_kernel<<<dim3(NGRP * NJ), dim3(NTHR), 0, stream>>>(
      ts, tsi, obs, tmaxp,
      i_win, i_bin, i_wmid, i_bmid, i_wout, i_bout,
      v_win, v_bin, v_wmid, v_bmid, v_wout, v_bout,
      (float*)d_out, (u64t*)d_ws);
}

// Round 13
// 4305.787 us; speedup vs baseline: 1.7560x; 1.7560x over previous
//
#include <hip/hip_runtime.h>
#include <stdint.h>

// Online Neural CDE — R13: zero-sync architecture (R12) with INT16 weights +
// FP32 activations. 1 batch = 1 block = 1 CU (128 blocks x 512 threads).
// Weights quantized per-row to int16 (rel err ~1.5e-5, 20x finer than fp16,
// same bytes) by a prep kernel into chunk-tiled layouts in d_ws:
//   scales[2816 f32] | wv 64KB | wm1 128KB | wl4 1MB | wm0 128KB
// m0 is copied once into LDS (swizzled, conflict-light); v_win, v_wmid[1],
// v_wout stream from the XCD L2 every eval (~1.2MB, L2-resident).
// Dequant inline: sext->cvt->fma with the row scale deferred (float(q) exact).
// ODE state y/k fp32 in registers; h1-h3 fp32 in LDS; precise tanh/softplus.
// No inter-block communication of any kind (R3-R11's ~5.1ms latency wall).

#define NB   128
#define NTHR 512

// d_ws byte layout (total 1,387,520 B)
#define SC_OFF   0u        // 2816 f32: wv[0..255] m1[256..511] l4[512..2559] m0[2560..2815]
#define WV_OFF   11264u
#define WM1_OFF  76800u
#define WL4_OFF  207872u
#define WM0_OFF  1256448u

static __device__ __forceinline__ float qmac2(uint32_t q, float h0, float h1, float acc) {
  acc = fmaf((float)(short)(q & 0xffffu), h0, acc);
  return fmaf((float)(short)(q >> 16), h1, acc);
}

// precise softplus: max(x,0) + log1p(exp(-|x|))
static __device__ __forceinline__ float sp(float x) {
  return fmaxf(x, 0.f) + log1pf(expf(-fabsf(x)));
}

// np.searchsorted(kn, t, 'right') - 1, clipped to [0, 62]; 64 knots.
static __device__ __forceinline__ int seg_idx(const float* kn, float t) {
  int lo = 0, hi = 64;
  while (lo < hi) { int mid = (lo + hi) >> 1; if (kn[mid] <= t) lo = mid + 1; else hi = mid; }
  int jj = lo - 1;
  return jj < 0 ? 0 : (jj > 62 ? 62 : jj);
}

// ---- prep: per-row int16 quantization into chunk-tiled streaming layouts ----
// rows: [0,256) v_win | [256,512) v_wmid[1] | [512,2560) v_wout | [2560,2816) v_wmid[0]
__global__ void prep_kernel(const float* __restrict__ v_win,
                            const float* __restrict__ v_wmid,
                            const float* __restrict__ v_wout,
                            unsigned char* __restrict__ wsb) {
  float* scales = (float*)(wsb + SC_OFF);
  short* wv  = (short*)(wsb + WV_OFF);
  short* wm1 = (short*)(wsb + WM1_OFF);
  short* wl4 = (short*)(wsb + WL4_OFF);
  short* wm0 = (short*)(wsb + WM0_OFF);
  const int r = blockIdx.x, lane = threadIdx.x;
  const float* src;
  int n, si;
  if (r < 256)       { src = v_win  + (size_t)r * 128;                n = 128; si = r; }
  else if (r < 512)  { src = v_wmid + 65536 + (size_t)(r - 256) * 256; n = 256; si = r; }
  else if (r < 2560) { src = v_wout + (size_t)(r - 512) * 256;         n = 256; si = r; }
  else               { src = v_wmid + (size_t)(r - 2560) * 256;        n = 256; si = r; }
  float m = 0.f;
  for (int i = lane; i < n; i += 64) m = fmaxf(m, fabsf(src[i]));
#pragma unroll
  for (int off = 32; off; off >>= 1) m = fmaxf(m, __shfl_xor(m, off));
  const float inv = (m > 0.f) ? 32767.f / m : 0.f;
  if (lane == 0) scales[si] = (m > 0.f) ? m / 32767.f : 1.f;
  for (int i = lane; i < n; i += 64) {
    short q = (short)rintf(src[i] * inv);
    if (r < 256) {
      int hf = i >> 6, c = (i & 63) >> 3, e = i & 7;
      wv[c * 4096 + (2 * r + hf) * 8 + e] = q;
    } else if (r < 512) {
      int row = r - 256, hf = i >> 7, c = (i & 127) >> 3, e = i & 7;
      wm1[c * 4096 + (2 * row + hf) * 8 + e] = q;
    } else if (r < 2560) {
      int row = r - 512;
      wl4[((row & 3) * 32 + (i >> 3)) * 4096 + (row >> 2) * 8 + (i & 7)] = q;
    } else {
      int row = r - 2560;
      wm0[(size_t)row * 256 + i] = q;
    }
  }
}

__global__ void __launch_bounds__(NTHR)
ncde_kernel(const float* __restrict__ ts, const float* __restrict__ tsi,
            const float* __restrict__ obs, const float* __restrict__ tmax,
            const float* __restrict__ i_win, const float* __restrict__ i_bin,
            const float* __restrict__ i_wmid, const float* __restrict__ i_bmid,
            const float* __restrict__ i_wout, const float* __restrict__ i_bout,
            const float* __restrict__ v_wmid, const float* __restrict__ v_bin,
            const float* __restrict__ v_bmid, const float* __restrict__ v_bout,
            const unsigned char* __restrict__ wsb, float* __restrict__ out) {
  __shared__ __align__(16) uint32_t s_m0[256][132];   // int16-pair m0, swizzled
  __shared__ __align__(16) float s_yin[132];
  __shared__ __align__(16) float s_h1[256];
  __shared__ __align__(16) float s_h2[256];
  __shared__ __align__(16) float s_h3[256];
  __shared__ __align__(16) float s_ts[64];
  __shared__ __align__(16) float s_kn[64];
  __shared__ float s_dx[16];
  __shared__ float s_x0[16];
  __shared__ unsigned char s_sj[128];

  const int t = threadIdx.x;
  const int b = blockIdx.x;
  const int o = t >> 1, half = t & 1;
  const bool owner = (t & 3) == 0;
  const int h = t >> 2;

  const float* scales = (const float*)(wsb + SC_OFF);
  const uint4* wvp  = ((const uint4*)(wsb + WV_OFF)) + t;
  const uint4* wm1p = ((const uint4*)(wsb + WM1_OFF)) + t;
  const uint4* wl4p = ((const uint4*)(wsb + WL4_OFF)) + t;

  if (t < 64) { s_ts[t] = ts[b * 64 + t]; s_kn[t] = tsi[b * 64 + t]; }
  const float tm = tmax[b];
  const float bl1 = v_bin[o];
  const float bm0 = v_bmid[o];
  const float bm1 = v_bmid[256 + o];
  const float4 vb4 = *(const float4*)(v_bout + 4 * t);
  const float sc_wv = scales[o];
  const float sc_m1 = scales[256 + o];
  const float sc_m0 = scales[2560 + o];
  const float4 sc_l4 = *(const float4*)(scales + 512 + 4 * t);
  __syncthreads();

  // m0 -> LDS (coalesced u32 copy, quartet-breaking swizzle on cols)
  {
    const uint32_t* wm0u = (const uint32_t*)(wsb + WM0_OFF);
    for (int idx = t; idx < 32768; idx += NTHR) {
      int row = idx >> 7, k = idx & 127;
      s_m0[row][k ^ (((row >> 3) & 3) << 2)] = wm0u[idx];
    }
  }
  if (t < 127) {
    int li = t >> 1;
    float te = (t & 1) ? fmaf(0.5f, s_ts[li + 1] - s_ts[li], s_ts[li]) : s_ts[li];
    s_sj[t] = (unsigned char)seg_idx(s_kn, te);
  }
  __syncthreads();

  // ---------------- init MLP: y0 = MLP_i(x0) (one-time, fp32 weights) ------
  if (t < 16) {
    float t0 = s_ts[0];
    int sj = s_sj[0];
    float k0 = s_kn[sj], k1 = s_kn[sj + 1];
    float fr = (t0 - k0) / (k1 - k0);
    const float* ob = obs + ((size_t)b * 64 + sj) * 16 + t;
    s_x0[t] = fmaf(fr, ob[16] - ob[0], ob[0]);
  }
  __syncthreads();
  if (t < 256) {                       // L1i: o=t, 16 ins
    float acc = i_bin[t];
    const float* wr = i_win + (size_t)t * 16;
#pragma unroll
    for (int i = 0; i < 16; ++i) acc = fmaf(wr[i], s_x0[i], acc);
    s_h1[t] = sp(acc);
  }
  __syncthreads();
  {                                    // m0i: o, half over 128 ins
    float acc = 0.f;
    const float4* wq = (const float4*)(i_wmid + (size_t)o * 256 + half * 128);
    const float4* hp = (const float4*)(s_h1 + half * 128);
#pragma unroll
    for (int i = 0; i < 32; ++i) {
      float4 w = wq[i]; float4 hh = hp[i];
      acc = fmaf(w.x, hh.x, acc); acc = fmaf(w.y, hh.y, acc);
      acc = fmaf(w.z, hh.z, acc); acc = fmaf(w.w, hh.w, acc);
    }
    acc += __shfl_xor(acc, 1);
    if (!half) s_h2[o] = sp(acc + i_bmid[o]);
  }
  __syncthreads();
  {                                    // m1i
    float acc = 0.f;
    const float4* wq = (const float4*)(i_wmid + 65536 + (size_t)o * 256 + half * 128);
    const float4* hp = (const float4*)(s_h2 + half * 128);
#pragma unroll
    for (int i = 0; i < 32; ++i) {
      float4 w = wq[i]; float4 hh = hp[i];
      acc = fmaf(w.x, hh.x, acc); acc = fmaf(w.y, hh.y, acc);
      acc = fmaf(w.z, hh.z, acc); acc = fmaf(w.w, hh.w, acc);
    }
    acc += __shfl_xor(acc, 1);
    if (!half) s_h3[o] = sp(acc + i_bmid[256 + o]);
  }
  __syncthreads();
  float yreg = 0.f, kreg = 0.f, kacc = 0.f;
  {                                    // L4i: row h=t>>2, quarter q=t&3
    float acc = 0.f;
    const float4* wq = (const float4*)(i_wout + (size_t)h * 256 + (t & 3) * 64);
    const float4* hp = (const float4*)(s_h3 + (t & 3) * 64);
#pragma unroll
    for (int i = 0; i < 16; ++i) {
      float4 w = wq[i]; float4 hh = hp[i];
      acc = fmaf(w.x, hh.x, acc); acc = fmaf(w.y, hh.y, acc);
      acc = fmaf(w.z, hh.z, acc); acc = fmaf(w.w, hh.w, acc);
    }
    acc += __shfl_xor(acc, 1);
    acc += __shfl_xor(acc, 2);
    if (owner) {
      yreg = acc + i_bout[h];
      out[(size_t)b * 8192 + h] = (s_ts[0] <= tm) ? yreg : -99.f;
    }
  }
  __syncthreads();

  // ---------------- RK4 over 63 intervals, fully block-local ---------------
#pragma unroll 1
  for (int l = 0; l < 63; ++l) {
    const float tl1 = s_ts[l + 1];
    const float dt = tl1 - s_ts[l];
#pragma unroll 1
    for (int e = 0; e < 4; ++e) {
      // phase 0: owners publish y_in; 16 lanes compute dx(t_e)
      if (owner) {
        float ce = (e == 0) ? 0.f : ((e == 3) ? 1.f : 0.5f);
        s_yin[h] = fmaf(ce * dt, kreg, yreg);
      }
      if (t < 16) {
        int ti = 2 * l + ((e == 0) ? 0 : ((e == 3) ? 2 : 1));
        int sj = s_sj[ti];
        const float* ob = obs + ((size_t)b * 64 + sj) * 16 + t;
        s_dx[t] = (ob[16] - ob[0]) / (s_kn[sj + 1] - s_kn[sj]);
      }
      __syncthreads();
      // L1 (streamed int16): row o, half over 64 y-ins
      {
        float acc = 0.f;
#pragma unroll
        for (int c = 0; c < 8; ++c) {
          uint4 w = wvp[c * 512];
          float4 ya = *(const float4*)(s_yin + half * 64 + 8 * c);
          float4 yb = *(const float4*)(s_yin + half * 64 + 8 * c + 4);
          acc = qmac2(w.x, ya.x, ya.y, acc);
          acc = qmac2(w.y, ya.z, ya.w, acc);
          acc = qmac2(w.z, yb.x, yb.y, acc);
          acc = qmac2(w.w, yb.z, yb.w, acc);
        }
        acc += __shfl_xor(acc, 1);
        if (!half) s_h1[o] = sp(acc * sc_wv + bl1);
      }
      __syncthreads();
      // m0 (LDS int16): row o, half over 128 ins
      {
        float acc = 0.f;
        const int swz = ((o >> 3) & 3) << 2;
        const uint32_t* wr = &s_m0[o][0];
#pragma unroll
        for (int k = 0; k < 16; ++k) {
          uint4 w = *(const uint4*)(wr + (((half * 64 + 4 * k)) ^ swz));
          float4 ha = *(const float4*)(s_h1 + half * 128 + 8 * k);
          float4 hb = *(const float4*)(s_h1 + half * 128 + 8 * k + 4);
          acc = qmac2(w.x, ha.x, ha.y, acc);
          acc = qmac2(w.y, ha.z, ha.w, acc);
          acc = qmac2(w.z, hb.x, hb.y, acc);
          acc = qmac2(w.w, hb.z, hb.w, acc);
        }
        acc += __shfl_xor(acc, 1);
        if (!half) s_h2[o] = sp(acc * sc_m0 + bm0);
      }
      __syncthreads();
      // m1 (streamed int16): row o, half over 128 ins
      {
        float acc = 0.f;
#pragma unroll 4
        for (int c = 0; c < 16; ++c) {
          uint4 w = wm1p[c * 512];
          float4 ha = *(const float4*)(s_h2 + half * 128 + 8 * c);
          float4 hb = *(const float4*)(s_h2 + half * 128 + 8 * c + 4);
          acc = qmac2(w.x, ha.x, ha.y, acc);
          acc = qmac2(w.y, ha.z, ha.w, acc);
          acc = qmac2(w.z, hb.x, hb.y, acc);
          acc = qmac2(w.w, hb.z, hb.w, acc);
        }
        acc += __shfl_xor(acc, 1);
        if (!half) s_h3[o] = sp(acc * sc_m1 + bm1);
      }
      __syncthreads();
      // L4 (streamed int16, 1MB): rows 4t..4t+3, full 256-dot each
      {
        float z0 = 0.f, z1 = 0.f, z2 = 0.f, z3 = 0.f;
#pragma unroll 4
        for (int cc = 0; cc < 32; ++cc) {
          float4 ha = *(const float4*)(s_h3 + 8 * cc);
          float4 hb = *(const float4*)(s_h3 + 8 * cc + 4);
          uint4 w0 = wl4p[(0 * 32 + cc) * 512];
          uint4 w1 = wl4p[(1 * 32 + cc) * 512];
          uint4 w2 = wl4p[(2 * 32 + cc) * 512];
          uint4 w3 = wl4p[(3 * 32 + cc) * 512];
          z0 = qmac2(w0.x, ha.x, ha.y, z0); z0 = qmac2(w0.y, ha.z, ha.w, z0);
          z0 = qmac2(w0.z, hb.x, hb.y, z0); z0 = qmac2(w0.w, hb.z, hb.w, z0);
          z1 = qmac2(w1.x, ha.x, ha.y, z1); z1 = qmac2(w1.y, ha.z, ha.w, z1);
          z1 = qmac2(w1.z, hb.x, hb.y, z1); z1 = qmac2(w1.w, hb.z, hb.w, z1);
          z2 = qmac2(w2.x, ha.x, ha.y, z2); z2 = qmac2(w2.y, ha.z, ha.w, z2);
          z2 = qmac2(w2.z, hb.x, hb.y, z2); z2 = qmac2(w2.w, hb.z, hb.w, z2);
          z3 = qmac2(w3.x, ha.x, ha.y, z3); z3 = qmac2(w3.y, ha.z, ha.w, z3);
          z3 = qmac2(w3.z, hb.x, hb.y, z3); z3 = qmac2(w3.w, hb.z, hb.w, z3);
        }
        const int d0 = 4 * (t & 3);
        float kv = 0.f;
        kv = fmaf(tanhf(fmaf(z0, sc_l4.x, vb4.x)), s_dx[d0 + 0], kv);
        kv = fmaf(tanhf(fmaf(z1, sc_l4.y, vb4.y)), s_dx[d0 + 1], kv);
        kv = fmaf(tanhf(fmaf(z2, sc_l4.z, vb4.z)), s_dx[d0 + 2], kv);
        kv = fmaf(tanhf(fmaf(z3, sc_l4.w, vb4.w)), s_dx[d0 + 3], kv);
        kv += __shfl_xor(kv, 1);
        kv += __shfl_xor(kv, 2);
        if (owner) {
          kreg = kv;
          if (e == 0) kacc = kv;
          else kacc = fmaf((e == 3) ? 1.f : 2.f, kv, kacc);
          if (e == 3) {
            yreg = fmaf(dt * (1.f / 6.f), kacc, yreg);
            out[(size_t)b * 8192 + (size_t)(l + 1) * 128 + h] =
                (tl1 <= tm) ? yreg : -99.f;
          }
        }
      }
      __syncthreads();   // protect s_yin/s_dx/s_h3 before next phase-0
    }
  }
}

extern "C" void kernel_launch(void* const* d_in, const int* in_sizes, int n_in,
                              void* d_out, int out_size, void* d_ws, size_t ws_size,
                              hipStream_t stream) {
  const float* ts     = (const float*)d_in[0];
  const float* tsi    = (const float*)d_in[1];
  const float* obs    = (const float*)d_in[2];
  const float* tmaxp  = (const float*)d_in[3];
  const float* i_win  = (const float*)d_in[4];
  const float* i_bin  = (const float*)d_in[5];
  const float* i_wmid = (const float*)d_in[6];
  const float* i_bmid = (const float*)d_in[7];
  const float* i_wout = (const float*)d_in[8];
  const float* i_bout = (const float*)d_in[9];
  const float* v_win  = (const float*)d_in[10];
  const float* v_bin  = (const float*)d_in[11];
  const float* v_wmid = (const float*)d_in[12];
  const float* v_bmid = (const float*)d_in[13];
  const float* v_wout = (const float*)d_in[14];
  const float* v_bout = (const float*)d_in[15];

  unsigned char* wsb = (unsigned char*)d_ws;   // needs 1,387,520 B

  prep_kernel<<<dim3(2816), dim3(64), 0, stream>>>(v_win, v_wmid, v_wout, wsb);
  ncde_kernel<<<dim3(NB), dim3(NTHR), 0, stream>>>(
      ts, tsi, obs, tmaxp,
      i_win, i_bin, i_wmid, i_bmid, i_wout, i_bout,
      v_wmid, v_bin, v_bmid, v_bout,
      wsb, (float*)d_out);
}